// Round 1
// baseline (1427.638 us; speedup 1.0000x reference)
//
#include <hip/hip_runtime.h>

#define WIDTH 128
#define SLOPE 0.01f
#define ROWS_PER_BLOCK 8

// Monotone mapping float -> uint32 so unsigned integer min == float min.
__device__ __forceinline__ unsigned mapf(float f) {
    unsigned b = __float_as_uint(f);
    return (b & 0x80000000u) ? ~b : (b | 0x80000000u);
}
__device__ __forceinline__ float unmapf(unsigned u) {
    unsigned b = (u & 0x80000000u) ? (u ^ 0x80000000u) : ~u;
    return __uint_as_float(b);
}

// Per-edge: atomically min x_src[src] into minbuf[dst].
// 32 lanes per edge, float4 per lane (128 floats / edge).
__global__ void edge_min_kernel(const float* __restrict__ x_src,
                                const int* __restrict__ e,
                                unsigned* __restrict__ minbuf,
                                int E) {
    int gt = blockIdx.x * blockDim.x + threadIdx.x;
    int edge = gt >> 5;
    int lane = gt & 31;
    if (edge >= E) return;
    int src = e[edge];          // e[0] row = src indices
    int dst = e[E + edge];      // e[1] row = dst indices
    float4 v = reinterpret_cast<const float4*>(x_src)[(size_t)src * 32 + lane];
    unsigned* base = minbuf + (size_t)dst * WIDTH + lane * 4;
    atomicMin(base + 0, mapf(v.x));
    atomicMin(base + 1, mapf(v.y));
    atomicMin(base + 2, mapf(v.z));
    atomicMin(base + 3, mapf(v.w));
}

// Fused: maxes = (empty ? 0 : x_dst - min_src); h = [x_dst, maxes] @ W + b;
// out = x_dst + leaky_relu(h)
__global__ void mlp_kernel(const float* __restrict__ x_dst,
                           const unsigned* __restrict__ minbuf,
                           const float* __restrict__ Wg,
                           const float* __restrict__ bias,
                           float* __restrict__ out,
                           int M) {
    __shared__ float cat[ROWS_PER_BLOCK][2 * WIDTH];
    int lt = threadIdx.x;
    int rl = lt >> 5;      // row-slot within block
    int lane = lt & 31;    // 32 lanes per row, 4 cols each
    int row = blockIdx.x * ROWS_PER_BLOCK + rl;
    if (row >= M) return;  // M divisible by ROWS_PER_BLOCK -> block-uniform

    float4 xd = reinterpret_cast<const float4*>(x_dst)[(size_t)row * 32 + lane];
    uint4 u = reinterpret_cast<const uint4*>(minbuf)[(size_t)row * 32 + lane];
    float4 mx;
    mx.x = (u.x == 0xFFFFFFFFu) ? 0.0f : xd.x - unmapf(u.x);
    mx.y = (u.y == 0xFFFFFFFFu) ? 0.0f : xd.y - unmapf(u.y);
    mx.z = (u.z == 0xFFFFFFFFu) ? 0.0f : xd.z - unmapf(u.z);
    mx.w = (u.w == 0xFFFFFFFFu) ? 0.0f : xd.w - unmapf(u.w);

    int c = lane * 4;
    cat[rl][c + 0] = xd.x;
    cat[rl][c + 1] = xd.y;
    cat[rl][c + 2] = xd.z;
    cat[rl][c + 3] = xd.w;
    cat[rl][WIDTH + c + 0] = mx.x;
    cat[rl][WIDTH + c + 1] = mx.y;
    cat[rl][WIDTH + c + 2] = mx.z;
    cat[rl][WIDTH + c + 3] = mx.w;
    __syncthreads();

    float4 acc = reinterpret_cast<const float4*>(bias)[lane];
    const float4* W4 = reinterpret_cast<const float4*>(Wg);
    #pragma unroll 8
    for (int k = 0; k < 2 * WIDTH; ++k) {
        float a = cat[rl][k];             // LDS broadcast across the 32 lanes
        float4 w = W4[k * 32 + lane];     // coalesced, L1/L2-resident
        acc.x = fmaf(a, w.x, acc.x);
        acc.y = fmaf(a, w.y, acc.y);
        acc.z = fmaf(a, w.z, acc.z);
        acc.w = fmaf(a, w.w, acc.w);
    }

    float4 r;
    r.x = xd.x + (acc.x > 0.0f ? acc.x : SLOPE * acc.x);
    r.y = xd.y + (acc.y > 0.0f ? acc.y : SLOPE * acc.y);
    r.z = xd.z + (acc.z > 0.0f ? acc.z : SLOPE * acc.z);
    r.w = xd.w + (acc.w > 0.0f ? acc.w : SLOPE * acc.w);
    reinterpret_cast<float4*>(out)[(size_t)row * 32 + lane] = r;
}

extern "C" void kernel_launch(void* const* d_in, const int* in_sizes, int n_in,
                              void* d_out, int out_size, void* d_ws, size_t ws_size,
                              hipStream_t stream) {
    const float* x_src = (const float*)d_in[0];
    const float* x_dst = (const float*)d_in[1];
    const int*   e     = (const int*)d_in[2];
    const float* W     = (const float*)d_in[3];
    const float* bias  = (const float*)d_in[4];
    float* out = (float*)d_out;

    int E = in_sizes[2] / 2;       // 800000
    int M = in_sizes[1] / WIDTH;   // 100000 dst nodes

    unsigned* minbuf = (unsigned*)d_ws;
    size_t minbytes = (size_t)M * WIDTH * sizeof(unsigned);

    // sentinel 0xFFFFFFFF == mapped +NaN: larger than any real mapped value,
    // and doubles as the "no edges touched this dst" flag.
    hipMemsetAsync(d_ws, 0xFF, minbytes, stream);

    long long ethreads = (long long)E * 32;
    int eblocks = (int)((ethreads + 255) / 256);
    edge_min_kernel<<<eblocks, 256, 0, stream>>>(x_src, e, minbuf, E);

    int mblocks = (M + ROWS_PER_BLOCK - 1) / ROWS_PER_BLOCK;
    mlp_kernel<<<mblocks, 256, 0, stream>>>(x_dst, minbuf, W, bias, out, M);
}

// Round 2
// 704.513 us; speedup vs baseline: 2.0264x; 2.0264x over previous
//
#include <hip/hip_runtime.h>

#define WIDTH 128
#define SLOPE 0.01f
#define ROWS_PER_BLOCK 8
#define SCAN_THREADS 1024

// ---------------- CSR build: counting sort of edges by dst ----------------

__global__ void hist_kernel(const int* __restrict__ e,
                            unsigned* __restrict__ counts, int E) {
    int i = blockIdx.x * blockDim.x + threadIdx.x;
    if (i < E) atomicAdd(&counts[e[E + i]], 1u);
}

// Single-block exclusive scan over M counts -> offsets[0..M], cursor[0..M-1].
__global__ void scan_kernel(const unsigned* __restrict__ counts,
                            int* __restrict__ offsets,
                            int* __restrict__ cursor, int M) {
    __shared__ unsigned sums[SCAN_THREADS];
    int t = threadIdx.x;
    int chunk = (M + SCAN_THREADS - 1) / SCAN_THREADS;
    int beg = t * chunk;
    int end = min(beg + chunk, M);
    unsigned s = 0;
    for (int i = beg; i < end; ++i) s += counts[i];
    sums[t] = s;
    __syncthreads();
    // Hillis-Steele inclusive scan over the 1024 chunk sums
    for (int off = 1; off < SCAN_THREADS; off <<= 1) {
        unsigned v = (t >= off) ? sums[t - off] : 0u;
        __syncthreads();
        sums[t] += v;
        __syncthreads();
    }
    unsigned run = (t == 0) ? 0u : sums[t - 1];  // exclusive base of this chunk
    for (int i = beg; i < end; ++i) {
        offsets[i] = (int)run;
        cursor[i]  = (int)run;
        run += counts[i];
    }
    if (t == SCAN_THREADS - 1) offsets[M] = (int)run;  // == E
}

__global__ void scatter_kernel(const int* __restrict__ e,
                               int* __restrict__ cursor,
                               int* __restrict__ csr_src, int E) {
    int i = blockIdx.x * blockDim.x + threadIdx.x;
    if (i < E) {
        int dst = e[E + i];
        int pos = atomicAdd(&cursor[dst], 1);
        csr_src[pos] = e[i];  // src index
    }
}

// ---------------- Fused: register min-reduce + MLP + residual ----------------
// maxes = (deg>0 ? x_dst - min_{edges}(x_src) : 0)   [exact: rounding monotone]
// out   = x_dst + leaky_relu([x_dst, maxes] @ W + b)

__global__ void fused_kernel(const float* __restrict__ x_src,
                             const float* __restrict__ x_dst,
                             const int* __restrict__ offsets,
                             const int* __restrict__ csr_src,
                             const float* __restrict__ Wg,
                             const float* __restrict__ bias,
                             float* __restrict__ out, int M) {
    __shared__ float cat[ROWS_PER_BLOCK][2 * WIDTH];
    int lt = threadIdx.x;
    int rl = lt >> 5;      // row-slot within block
    int lane = lt & 31;    // 32 lanes per row, float4 each
    int row = blockIdx.x * ROWS_PER_BLOCK + rl;
    if (row >= M) return;  // M % ROWS_PER_BLOCK == 0 -> block-uniform

    int beg = offsets[row];
    int end = offsets[row + 1];

    const float4* xs4 = reinterpret_cast<const float4*>(x_src);
    float4 mn = make_float4(INFINITY, INFINITY, INFINITY, INFINITY);
    for (int i = beg; i < end; ++i) {
        int src = csr_src[i];                    // broadcast across 32 lanes
        float4 v = xs4[(size_t)src * 32 + lane]; // coalesced 512B row read
        mn.x = fminf(mn.x, v.x);
        mn.y = fminf(mn.y, v.y);
        mn.z = fminf(mn.z, v.z);
        mn.w = fminf(mn.w, v.w);
    }

    float4 xd = reinterpret_cast<const float4*>(x_dst)[(size_t)row * 32 + lane];
    float4 mx;
    if (end > beg) {
        mx.x = xd.x - mn.x; mx.y = xd.y - mn.y;
        mx.z = xd.z - mn.z; mx.w = xd.w - mn.w;
    } else {
        mx = make_float4(0.f, 0.f, 0.f, 0.f);
    }

    reinterpret_cast<float4*>(&cat[rl][0])[lane] = xd;
    reinterpret_cast<float4*>(&cat[rl][WIDTH])[lane] = mx;
    __syncthreads();

    float4 acc = reinterpret_cast<const float4*>(bias)[lane];
    const float4* W4 = reinterpret_cast<const float4*>(Wg);
    #pragma unroll 8
    for (int k = 0; k < 2 * WIDTH; ++k) {
        float a = cat[rl][k];           // LDS broadcast
        float4 w = W4[k * 32 + lane];   // coalesced, L1/L2-resident
        acc.x = fmaf(a, w.x, acc.x);
        acc.y = fmaf(a, w.y, acc.y);
        acc.z = fmaf(a, w.z, acc.z);
        acc.w = fmaf(a, w.w, acc.w);
    }

    float4 r;
    r.x = xd.x + (acc.x > 0.0f ? acc.x : SLOPE * acc.x);
    r.y = xd.y + (acc.y > 0.0f ? acc.y : SLOPE * acc.y);
    r.z = xd.z + (acc.z > 0.0f ? acc.z : SLOPE * acc.z);
    r.w = xd.w + (acc.w > 0.0f ? acc.w : SLOPE * acc.w);
    reinterpret_cast<float4*>(out)[(size_t)row * 32 + lane] = r;
}

extern "C" void kernel_launch(void* const* d_in, const int* in_sizes, int n_in,
                              void* d_out, int out_size, void* d_ws, size_t ws_size,
                              hipStream_t stream) {
    const float* x_src = (const float*)d_in[0];
    const float* x_dst = (const float*)d_in[1];
    const int*   e     = (const int*)d_in[2];
    const float* W     = (const float*)d_in[3];
    const float* bias  = (const float*)d_in[4];
    float* out = (float*)d_out;

    int E = in_sizes[2] / 2;       // 800000
    int M = in_sizes[1] / WIDTH;   // 100000 dst nodes

    // Workspace layout (all 4-byte ints): counts[M] | offsets[M+1] | cursor[M] | csr_src[E]
    unsigned* counts  = (unsigned*)d_ws;
    int*      offsets = (int*)(counts + M);
    int*      cursor  = offsets + (M + 1);
    int*      csr_src = cursor + M;

    hipMemsetAsync(counts, 0, (size_t)M * sizeof(unsigned), stream);

    int eblocks = (E + 255) / 256;
    hist_kernel<<<eblocks, 256, 0, stream>>>(e, counts, E);
    scan_kernel<<<1, SCAN_THREADS, 0, stream>>>(counts, offsets, cursor, M);
    scatter_kernel<<<eblocks, 256, 0, stream>>>(e, cursor, csr_src, E);

    int mblocks = (M + ROWS_PER_BLOCK - 1) / ROWS_PER_BLOCK;
    fused_kernel<<<mblocks, 256, 0, stream>>>(x_src, x_dst, offsets, csr_src,
                                              W, bias, out, M);
}